// Round 8
// baseline (742.779 us; speedup 1.0000x reference)
//
#include <hip/hip_runtime.h>
#include <math.h>

// MAMBAFlow split-bf16 MFMA, round 8.
// = round 6 (passing) + attn fixes: bank-rotated Vt transpose stores,
// uint2 P stores, 128 q-rows/block (halved KV refetch, 2x MFMA per barrier).
// Q/K stay SPLIT bf16 (round 7 proved single-bf16 QK loses 1.6e-3: score
// error is coherent per q-row, does not average over keys). V stays hi-only.

typedef float floatx4 __attribute__((ext_vector_type(4)));
typedef short shortx8 __attribute__((ext_vector_type(8)));

__device__ __forceinline__ unsigned short f2bf(float f) {
  unsigned u = __builtin_bit_cast(unsigned, f);
  u += 0x7FFFu + ((u >> 16) & 1u);  // RNE
  return (unsigned short)(u >> 16);
}
__device__ __forceinline__ float bf2f(unsigned short h) {
  unsigned u = ((unsigned)h) << 16;
  return __builtin_bit_cast(float, u);
}
__device__ __forceinline__ void split8(float4 a, float4 b, uint4& uh, uint4& ul) {
  float fv[8] = {a.x, a.y, a.z, a.w, b.x, b.y, b.z, b.w};
  unsigned hh[8], ll[8];
#pragma unroll
  for (int j = 0; j < 8; ++j) {
    unsigned short h = f2bf(fv[j]);
    hh[j] = h;
    ll[j] = f2bf(fv[j] - bf2f(h));
  }
  uh = make_uint4(hh[0] | (hh[1] << 16), hh[2] | (hh[3] << 16),
                  hh[4] | (hh[5] << 16), hh[6] | (hh[7] << 16));
  ul = make_uint4(ll[0] | (ll[1] << 16), ll[2] | (ll[3] << 16),
                  ll[4] | (ll[5] << 16), ll[6] | (ll[7] << 16));
}
__device__ __forceinline__ shortx8 lds_frag(const unsigned short* S, int row, int u) {
  uint4 v = *(const uint4*)(S + row * 64 + ((u ^ (row & 7)) << 3));
  return __builtin_bit_cast(shortx8, v);
}
__device__ __forceinline__ shortx8 gfrag(const unsigned short* p) {
  return __builtin_bit_cast(shortx8, *(const uint4*)p);
}
__device__ __forceinline__ floatx4 mfma16(shortx8 a, shortx8 b, floatx4 c) {
  return __builtin_amdgcn_mfma_f32_16x16x32_bf16(a, b, c, 0, 0, 0);
}
__device__ __forceinline__ float wave_sum64(float v) {
#pragma unroll
  for (int m = 1; m < 64; m <<= 1) v += __shfl_xor(v, m);
  return v;
}

// ---------------- weights fp32 -> split bf16 planes ----------------
__global__ __launch_bounds__(256) void wconv_k(
    const float* __restrict__ gw, const float* __restrict__ ipw,
    const float* __restrict__ ow, const float* __restrict__ d1w,
    unsigned short* __restrict__ dh, unsigned short* __restrict__ dl) {
  int i = (blockIdx.x * 256 + threadIdx.x) * 8;
  const float* src;
  if (i < 262144) src = gw + i;
  else if (i < 458752) src = ipw + (i - 262144);
  else if (i < 524288) src = ow + (i - 458752);
  else src = d1w + (i - 524288);
  uint4 uh, ul;
  split8(*(const float4*)src, *(const float4*)(src + 4), uh, ul);
  *(uint4*)(dh + i) = uh;
  *(uint4*)(dl + i) = ul;
}

// ---------------- embed weights: [256][33] -> split planes [2][256][64] ----------------
__global__ __launch_bounds__(256) void wconv2_k(
    const float* __restrict__ Wi, const float* __restrict__ Wq,
    unsigned short* __restrict__ eh, unsigned short* __restrict__ el) {
  int idx = blockIdx.x * 256 + threadIdx.x;
  int sel = idx >> 14, rem = idx & 16383;
  int row = rem >> 6, k = rem & 63;
  float v = 0.f;
  if (k < 33) v = (sel ? Wq : Wi)[row * 33 + k];
  unsigned short h = f2bf(v);
  eh[idx] = h;
  el[idx] = f2bf(v - bf2f(h));
}

// ---------------- embed via MFMA: 64 tokens/block ----------------
__global__ __launch_bounds__(256) void embed_k(
    const float* __restrict__ sc, const float* __restrict__ sv,
    const float* __restrict__ qc, const float* __restrict__ tarr,
    const float* __restrict__ noise, const float* __restrict__ Bf,
    const float* __restrict__ bq, const float* __restrict__ bi,
    const unsigned short* __restrict__ Weh, const unsigned short* __restrict__ Wel,
    float* __restrict__ seq) {
  __shared__ unsigned short Ah[64 * 64];
  __shared__ unsigned short Al[64 * 64];
  __shared__ float teb[256];
  int tid = threadIdx.x;
  int bid = blockIdx.x;
  int chunk = bid & 15, half = (bid >> 4) & 1, b = bid >> 5;
  int rowbase = b * 2048 + half * 1024 + chunk * 64;
  {
    uint4 z = make_uint4(0, 0, 0, 0);
    *(uint4*)(Ah + tid * 8) = z;
    *(uint4*)(Ah + 2048 + tid * 8) = z;
    *(uint4*)(Al + tid * 8) = z;
    *(uint4*)(Al + 2048 + tid * 8) = z;
  }
  {
    float t = tarr[b];
    int dd = tid & 127;
    float e = t * __expf((float)dd * -0.07252236513367074f);
    float v = (tid < 128) ? sinf(e) : cosf(e);
    teb[tid] = v + (half ? bq : bi)[tid];
  }
  __syncthreads();
  {
    int tok = tid >> 2;
    int n = chunk * 64 + tok;
    const float* cp = (half ? qc : sc) + (size_t)(b * 1024 + n) * 2;
    float cx = cp[0], cy = cp[1];
#pragma unroll
    for (int jj = 0; jj < 4; ++jj) {
      int fr = (tid & 3) * 4 + jj;
      float px = cx * Bf[fr] + cy * Bf[16 + fr];
      float s = sinf(px), c = cosf(px);
      unsigned short sh = f2bf(s), ch = f2bf(c);
      int ks = fr, kc = 16 + fr;
      Ah[tok * 64 + (((ks >> 3) ^ (tok & 7)) << 3) + (ks & 7)] = sh;
      Al[tok * 64 + (((ks >> 3) ^ (tok & 7)) << 3) + (ks & 7)] = f2bf(s - bf2f(sh));
      Ah[tok * 64 + (((kc >> 3) ^ (tok & 7)) << 3) + (kc & 7)] = ch;
      Al[tok * 64 + (((kc >> 3) ^ (tok & 7)) << 3) + (kc & 7)] = f2bf(c - bf2f(ch));
    }
    if ((tid & 3) == 0) {
      float vv = (half ? noise : sv)[b * 1024 + n];
      unsigned short vh = f2bf(vv);
      Ah[tok * 64 + ((4 ^ (tok & 7)) << 3)] = vh;
      Al[tok * 64 + ((4 ^ (tok & 7)) << 3)] = f2bf(vv - bf2f(vh));
    }
  }
  __syncthreads();
  int w = tid >> 6, lane = tid & 63, lm = lane & 15, quad = lane >> 4;
  const unsigned short* Wb = Weh + half * 16384;
  const unsigned short* Wbl = Wel + half * 16384;
  floatx4 acc[4][4] = {};
#pragma unroll
  for (int s = 0; s < 2; ++s) {
    shortx8 afh[4], afl[4];
#pragma unroll
    for (int i = 0; i < 4; ++i) {
      afh[i] = lds_frag(Ah, i * 16 + lm, s * 4 + quad);
      afl[i] = lds_frag(Al, i * 16 + lm, s * 4 + quad);
    }
#pragma unroll
    for (int n = 0; n < 4; ++n) {
      int wr = w * 64 + n * 16 + lm;
      shortx8 bh = gfrag(Wb + wr * 64 + (s * 4 + quad) * 8);
      shortx8 bl = gfrag(Wbl + wr * 64 + (s * 4 + quad) * 8);
#pragma unroll
      for (int i = 0; i < 4; ++i) {
        acc[i][n] = mfma16(afl[i], bh, acc[i][n]);
        acc[i][n] = mfma16(afh[i], bl, acc[i][n]);
        acc[i][n] = mfma16(afh[i], bh, acc[i][n]);
      }
    }
  }
#pragma unroll
  for (int i = 0; i < 4; ++i)
#pragma unroll
    for (int n = 0; n < 4; ++n) {
      int col = w * 64 + n * 16 + lm;
      float te = teb[col];
#pragma unroll
      for (int r = 0; r < 4; ++r) {
        int tok = i * 16 + quad * 4 + r;
        seq[(size_t)(rowbase + tok) * 256 + col] = acc[i][n][r] + te;
      }
    }
}

// ---------------- layernorm + split xn planes + transposed Bu ----------------
__global__ __launch_bounds__(256) void ln_bu_k(
    const float* __restrict__ seq, const float* __restrict__ g,
    const float* __restrict__ be, const float* __restrict__ Bw,
    unsigned short* __restrict__ xnh, unsigned short* __restrict__ xnl,
    float* __restrict__ BuT) {
  int tid = threadIdx.x;
  int row = blockIdx.x * 4 + (tid >> 6);
  int lane = tid & 63;
  float4 x = *(const float4*)(seq + (size_t)row * 256 + lane * 4);
  float s1 = x.x + x.y + x.z + x.w;
  float s2 = x.x * x.x + x.y * x.y + x.z * x.z + x.w * x.w;
#pragma unroll
  for (int mk = 1; mk < 64; mk <<= 1) {
    s1 += __shfl_xor(s1, mk);
    s2 += __shfl_xor(s2, mk);
  }
  float mu = s1 * (1.0f / 256.0f);
  float var = s2 * (1.0f / 256.0f) - mu * mu;
  float rs = rsqrtf(var + 1e-5f);
  float4 gg = *(const float4*)(g + lane * 4);
  float4 bb = *(const float4*)(be + lane * 4);
  float xn0 = (x.x - mu) * rs * gg.x + bb.x;
  float xn1 = (x.y - mu) * rs * gg.y + bb.y;
  float xn2 = (x.z - mu) * rs * gg.z + bb.z;
  float xn3 = (x.w - mu) * rs * gg.w + bb.w;
  unsigned short h0 = f2bf(xn0), h1 = f2bf(xn1), h2 = f2bf(xn2), h3 = f2bf(xn3);
  *(ushort4*)(xnh + (size_t)row * 256 + lane * 4) = make_ushort4(h0, h1, h2, h3);
  *(ushort4*)(xnl + (size_t)row * 256 + lane * 4) =
      make_ushort4(f2bf(xn0 - bf2f(h0)), f2bf(xn1 - bf2f(h1)),
                   f2bf(xn2 - bf2f(h2)), f2bf(xn3 - bf2f(h3)));
#pragma unroll
  for (int s = 0; s < 8; ++s) {
    float4 bw = *(const float4*)(Bw + s * 256 + lane * 4);
    float p = xn0 * bw.x + xn1 * bw.y + xn2 * bw.z + xn3 * bw.w;
#pragma unroll
    for (int mk = 1; mk < 64; mk <<= 1) p += __shfl_xor(p, mk);
    if (lane == 0) BuT[(size_t)s * 32768 + row] = p;
  }
}

// ---------------- SSM scan: one wave per (b,s), coalesced ----------------
__global__ __launch_bounds__(256) void scan_k(
    const float* __restrict__ BuT, const float* __restrict__ A_log,
    float* __restrict__ hsT) {
  int tid = threadIdx.x;
  int wid = blockIdx.x * 4 + (tid >> 6);
  int lane = tid & 63;
  int b = wid >> 3, s = wid & 7;
  float A = -fminf(fmaxf(expf(A_log[s]), 1e-8f), 10.0f);
  float abar = expf(A * (1.0f / 2048.0f));
  size_t base = (size_t)s * 32768 + b * 2048 + lane * 32;
  const float4* bu4 = (const float4*)(BuT + base);
  float4 v[8];
#pragma unroll
  for (int k = 0; k < 8; ++k) v[k] = bu4[k];
  float bl = 0.f;
#pragma unroll
  for (int k = 0; k < 8; ++k) {
    bl = abar * bl + v[k].x;
    bl = abar * bl + v[k].y;
    bl = abar * bl + v[k].z;
    bl = abar * bl + v[k].w;
  }
  float a = expf(A * (32.0f / 2048.0f));
  float bb = bl;
#pragma unroll
  for (int off = 1; off < 64; off <<= 1) {
    float pa = __shfl_up(a, (unsigned)off);
    float pb = __shfl_up(bb, (unsigned)off);
    if (lane >= off) { bb = a * pb + bb; a = a * pa; }
  }
  float h = __shfl_up(bb, 1u);
  if (lane == 0) h = 0.f;
  float4* hp4 = (float4*)(hsT + base);
#pragma unroll
  for (int k = 0; k < 8; ++k) {
    float h0 = abar * h + v[k].x;
    float h1 = abar * h0 + v[k].y;
    float h2 = abar * h1 + v[k].z;
    float h3 = abar * h2 + v[k].w;
    hp4[k] = make_float4(h0, h1, h2, h3);
    h = h3;
  }
}

// ---------------- split-bf16 MFMA GEMM (LDS-staged 128x128) ----------------
// ASPLIT=1: A as hi/lo ushort planes. ASPLIT=0: A fp32, split in-register.
// MODE 0: fp32 C=acc+bias  MODE 1: relu  MODE 2: gate-SSM epilogue into seq
// MODE 3: split-plane ushort outputs (Ch,Cl)
template <int MODE, int ASPLIT>
__global__ __launch_bounds__(256, 2) void mgemm_k(
    const void* __restrict__ Aptr, const unsigned short* __restrict__ Alp,
    const unsigned short* __restrict__ Wh, const unsigned short* __restrict__ Wl,
    const float* __restrict__ bias, void* __restrict__ C0, void* __restrict__ C1,
    int ldc, int aClog, int aStride, int aBase,
    const float* __restrict__ hsT, const float* __restrict__ Cw,
    const float* __restrict__ Dp) {
  __shared__ unsigned short Ash[128 * 64];
  __shared__ unsigned short Asl[128 * 64];
  __shared__ unsigned short Bsh[128 * 64];
  __shared__ unsigned short Bsl[128 * 64];
  int tid = threadIdx.x;
  int n0 = blockIdx.x * 128, m0 = blockIdx.y * 128;
  int w = tid >> 6, lane = tid & 63;
  int wm = w & 1, wn = w >> 1;
  int lm = lane & 15, quad = lane >> 4;
  int sr = tid >> 3, scu = tid & 7;
  unsigned aMask = (1u << aClog) - 1u;
  floatx4 acc[4][4] = {};
  for (int kc = 0; kc < 4; ++kc) {
    uint4 ah[4], al[4], wh[4], wl[4];
#pragma unroll
    for (int p = 0; p < 4; ++p) {
      int am = m0 + sr + p * 32;
      int grow = ((am >> aClog) * aStride) + aBase + (int)((unsigned)am & aMask);
      if (ASPLIT) {
        const unsigned short* pa = (const unsigned short*)Aptr + (size_t)grow * 256 + kc * 64 + scu * 8;
        ah[p] = *(const uint4*)pa;
        al[p] = *(const uint4*)(Alp + (pa - (const unsigned short*)Aptr));
      } else {
        const float* pa = (const float*)Aptr + (size_t)grow * 256 + kc * 64 + scu * 8;
        split8(*(const float4*)pa, *(const float4*)(pa + 4), ah[p], al[p]);
      }
      const unsigned short* pw = Wh + (size_t)(n0 + sr + p * 32) * 256 + kc * 64 + scu * 8;
      wh[p] = *(const uint4*)pw;
      wl[p] = *(const uint4*)(Wl + (pw - Wh));
    }
    __syncthreads();
#pragma unroll
    for (int p = 0; p < 4; ++p) {
      int r = sr + p * 32;
      int off = r * 64 + ((scu ^ (r & 7)) << 3);
      *(uint4*)(Ash + off) = ah[p];
      *(uint4*)(Asl + off) = al[p];
      *(uint4*)(Bsh + off) = wh[p];
      *(uint4*)(Bsl + off) = wl[p];
    }
    __syncthreads();
#pragma unroll
    for (int s = 0; s < 2; ++s) {
      shortx8 afh[4], afl[4], bfh[4], bfl[4];
#pragma unroll
      for (int i = 0; i < 4; ++i) {
        int rr = wm * 64 + i * 16 + lm;
        afh[i] = lds_frag(Ash, rr, s * 4 + quad);
        afl[i] = lds_frag(Asl, rr, s * 4 + quad);
      }
#pragma unroll
      for (int n = 0; n < 4; ++n) {
        int rr = wn * 64 + n * 16 + lm;
        bfh[n] = lds_frag(Bsh, rr, s * 4 + quad);
        bfl[n] = lds_frag(Bsl, rr, s * 4 + quad);
      }
#pragma unroll
      for (int i = 0; i < 4; ++i)
#pragma unroll
        for (int n = 0; n < 4; ++n) {
          acc[i][n] = mfma16(afl[i], bfh[n], acc[i][n]);
          acc[i][n] = mfma16(afh[i], bfl[n], acc[i][n]);
          acc[i][n] = mfma16(afh[i], bfh[n], acc[i][n]);
        }
    }
  }
  if (MODE == 2) {
    float cw[4][8], dp4[4], bi4[4];
#pragma unroll
    for (int n = 0; n < 4; ++n) {
      int col = n0 + wn * 64 + n * 16 + lm;
      float4 c0 = *(const float4*)(Cw + (size_t)col * 8);
      float4 c1 = *(const float4*)(Cw + (size_t)col * 8 + 4);
      cw[n][0] = c0.x; cw[n][1] = c0.y; cw[n][2] = c0.z; cw[n][3] = c0.w;
      cw[n][4] = c1.x; cw[n][5] = c1.y; cw[n][6] = c1.z; cw[n][7] = c1.w;
      dp4[n] = Dp[col];
      bi4[n] = bias[col];
    }
    float* seqp = (float*)C0;
    const unsigned short* Ahp = (const unsigned short*)Aptr;
#pragma unroll
    for (int i = 0; i < 4; ++i)
#pragma unroll
      for (int r = 0; r < 4; ++r) {
        int row = m0 + wm * 64 + i * 16 + quad * 4 + r;
        float hv[8];
#pragma unroll
        for (int s = 0; s < 8; ++s) hv[s] = hsT[(size_t)s * 32768 + row];
        float* srow = seqp + (size_t)row * 256;
#pragma unroll
        for (int n = 0; n < 4; ++n) {
          int col = n0 + wn * 64 + n * 16 + lm;
          float xg = acc[i][n][r] + bi4[n];
          float gt = 1.0f / (1.0f + __expf(-xg));
          float xv = bf2f(Ahp[(size_t)row * 256 + col]) + bf2f(Alp[(size_t)row * 256 + col]);
          float y = dp4[n] * xv;
#pragma unroll
          for (int s = 0; s < 8; ++s) y += hv[s] * cw[n][s];
          srow[col] += gt * y;
        }
      }
  } else if (MODE == 3) {
    unsigned short* Ch = (unsigned short*)C0;
    unsigned short* Cl = (unsigned short*)C1;
#pragma unroll
    for (int i = 0; i < 4; ++i)
#pragma unroll
      for (int r = 0; r < 4; ++r) {
        int row = m0 + wm * 64 + i * 16 + quad * 4 + r;
#pragma unroll
        for (int n = 0; n < 4; ++n) {
          int col = n0 + wn * 64 + n * 16 + lm;
          float v = acc[i][n][r] + bias[col];
          unsigned short h = f2bf(v);
          Ch[(size_t)row * ldc + col] = h;
          Cl[(size_t)row * ldc + col] = f2bf(v - bf2f(h));
        }
      }
  } else {
    float* Cf = (float*)C0;
#pragma unroll
    for (int i = 0; i < 4; ++i)
#pragma unroll
      for (int r = 0; r < 4; ++r) {
        int row = m0 + wm * 64 + i * 16 + quad * 4 + r;
#pragma unroll
        for (int n = 0; n < 4; ++n) {
          int col = n0 + wn * 64 + n * 16 + lm;
          float v = acc[i][n][r] + bias[col];
          if (MODE == 1) v = fmaxf(v, 0.0f);
          Cf[(size_t)row * ldc + col] = v;
        }
      }
  }
}

// ---------------- flash attention: split-QK, hi-V, S^T, per-lane softmax ----------------
// Block = 128 q rows of one (b,h); wave owns 32 q (2 groups of 16).
__global__ __launch_bounds__(256, 4) void attn_k(
    const unsigned short* __restrict__ qh, const unsigned short* __restrict__ ql,
    const unsigned short* __restrict__ kvh, const unsigned short* __restrict__ kvl,
    float* __restrict__ ob) {
  __shared__ unsigned short Ksh[64 * 64];
  __shared__ unsigned short Ksl[64 * 64];
  __shared__ unsigned short Vt[64 * 64];      // V transposed [d][key], bf16-hi
  __shared__ unsigned short Ps[4 * 32 * 64];  // per-wave P [32 q][64 key]
  int tid = threadIdx.x;
  int bid = blockIdx.x;  // 8 qt | 4 h | 16 b
  int qt = bid & 7, bh = bid >> 3;
  int h = bh & 3, b = bh >> 2;
  int w = tid >> 6, lane = tid & 63, lm = lane & 15, quad = lane >> 4;
  int sr = tid >> 3, scu = tid & 7;
  unsigned short* Pw = Ps + w * 2048;
  shortx8 qfh[2][2], qfl[2][2];
#pragma unroll
  for (int g = 0; g < 2; ++g) {
    size_t qoff = (size_t)(b * 1024 + qt * 128 + w * 32 + g * 16 + lm) * 256 + h * 64;
#pragma unroll
    for (int s = 0; s < 2; ++s) {
      qfh[g][s] = gfrag(qh + qoff + s * 32 + quad * 8);
      qfl[g][s] = gfrag(ql + qoff + s * 32 + quad * 8);
    }
  }
  float lac[2] = {0.f, 0.f};
  floatx4 oacc[2][4] = {};
  const size_t kvbase = ((size_t)(b * 1024)) * 512 + h * 64;
  const float sc_l2 = 0.125f * 1.44269504089f;  // 1/sqrt(64)*log2(e)
  int vg = tid & 7, vk = (tid >> 3) * 2;
  for (int kt = 0; kt < 16; ++kt) {
    uint4 kh4[2], kl4[2];
#pragma unroll
    for (int p = 0; p < 2; ++p) {
      int r = sr + p * 32;
      size_t a = kvbase + (size_t)(kt * 64 + r) * 512 + scu * 8;
      kh4[p] = *(const uint4*)(kvh + a);
      kl4[p] = *(const uint4*)(kvl + a);
    }
    uint4 vv0 = *(const uint4*)(kvh + kvbase + (size_t)(kt * 64 + vk) * 512 + 256 + vg * 8);
    uint4 vv1 = *(const uint4*)(kvh + kvbase + (size_t)(kt * 64 + vk + 1) * 512 + 256 + vg * 8);
    __syncthreads();  // prior iter's K/V fragment reads complete
#pragma unroll
    for (int p = 0; p < 2; ++p) {
      int r = sr + p * 32;
      int off = r * 64 + ((scu ^ (r & 7)) << 3);
      *(uint4*)(Ksh + off) = kh4[p];
      *(uint4*)(Ksl + off) = kl4[p];
    }
    {
      shortx8 s0 = __builtin_bit_cast(shortx8, vv0);
      shortx8 s1 = __builtin_bit_cast(shortx8, vv1);
#pragma unroll
      for (int jj = 0; jj < 8; ++jj) {
        int j = (jj + vg) & 7;     // bank-rotated store: no 8-way conflict
        int d = vg * 8 + j;
        unsigned pack = ((unsigned)(unsigned short)s0[j]) |
                        (((unsigned)(unsigned short)s1[j]) << 16);
        *(unsigned*)(Vt + d * 64 + (((vk >> 3) ^ (d & 7)) << 3) + (vk & 7)) = pack;
      }
    }
    __syncthreads();
    // S^T = K · Q^T : rows = keys, cols = q
    floatx4 sacc[2][4] = {};
#pragma unroll
    for (int s = 0; s < 2; ++s) {
#pragma unroll
      for (int m = 0; m < 4; ++m) {
        shortx8 kfh = lds_frag(Ksh, m * 16 + lm, s * 4 + quad);
        shortx8 kfl = lds_frag(Ksl, m * 16 + lm, s * 4 + quad);
#pragma unroll
        for (int g = 0; g < 2; ++g) {
          sacc[g][m] = mfma16(kfl, qfh[g][s], sacc[g][m]);
          sacc[g][m] = mfma16(kfh, qfl[g][s], sacc[g][m]);
          sacc[g][m] = mfma16(kfh, qfh[g][s], sacc[g][m]);
        }
      }
    }
#pragma unroll
    for (int g = 0; g < 2; ++g)
#pragma unroll
      for (int m = 0; m < 4; ++m) {
        float p0 = exp2f(sacc[g][m][0] * sc_l2 - 12.0f);
        float p1 = exp2f(sacc[g][m][1] * sc_l2 - 12.0f);
        float p2 = exp2f(sacc[g][m][2] * sc_l2 - 12.0f);
        float p3 = exp2f(sacc[g][m][3] * sc_l2 - 12.0f);
        lac[g] += (p0 + p1) + (p2 + p3);
        int prow = g * 16 + lm;
        int u = (m * 2 + (quad >> 1)) ^ (lm & 7);
        unsigned short* base = Pw + prow * 64 + u * 8 + (quad & 1) * 4;
        *(uint2*)base = make_uint2(((unsigned)f2bf(p0)) | (((unsigned)f2bf(p1)) << 16),
                                   ((unsigned)f2bf(p2)) | (((unsigned)f2bf(p3)) << 16));
      }
#pragma unroll
    for (int s = 0; s < 2; ++s) {
      shortx8 vf[4];
#pragma unroll
      for (int n = 0; n < 4; ++n) vf[n] = lds_frag(Vt, n * 16 + lm, s * 4 + quad);
#pragma unroll
      for (int g = 0; g < 2; ++g) {
        shortx8 pf = lds_frag(Pw, g * 16 + lm, s * 4 + quad);
#pragma unroll
        for (int n = 0; n < 4; ++n) oacc[g][n] = mfma16(pf, vf[n], oacc[g][n]);
      }
    }
  }
#pragma unroll
  for (int g = 0; g < 2; ++g) {
    lac[g] += __shfl_xor(lac[g], 16);
    lac[g] += __shfl_xor(lac[g], 32);
    const size_t obase = ((size_t)(b * 1024 + qt * 128 + w * 32 + g * 16)) * 256 + h * 64;
#pragma unroll
    for (int r = 0; r < 4; ++r) {
      int row = quad * 4 + r;
      float inv = 1.0f / __shfl(lac[g], row);
#pragma unroll
      for (int n = 0; n < 4; ++n)
        ob[obase + (size_t)row * 256 + n * 16 + lm] = oacc[g][n][r] * inv;
    }
  }
}

// ---------------- final projection ----------------
__global__ __launch_bounds__(256) void dec2_k(const float* __restrict__ hb,
                                              const float* __restrict__ w2,
                                              const float* __restrict__ b2,
                                              float* __restrict__ out) {
  int tid = threadIdx.x;
  int m = blockIdx.x * 4 + (tid >> 6);
  int lane = tid & 63;
  float4 h4 = *(const float4*)(hb + (size_t)m * 256 + lane * 4);
  float4 w4 = *(const float4*)(w2 + lane * 4);
  float v = h4.x * w4.x + h4.y * w4.y + h4.z * w4.z + h4.w * w4.w;
  v = wave_sum64(v);
  if (lane == 0) out[m] = v + b2[0];
}

extern "C" void kernel_launch(void* const* d_in, const int* in_sizes, int n_in,
                              void* d_out, int out_size, void* d_ws, size_t ws_size,
                              hipStream_t stream) {
  const float* sparse_coords = (const float*)d_in[0];
  const float* sparse_values = (const float*)d_in[1];
  const float* query_coords  = (const float*)d_in[2];
  const float* t_arr         = (const float*)d_in[3];
  const float* noise         = (const float*)d_in[4];
  const float* B_f           = (const float*)d_in[5];
  const float* Wq_in         = (const float*)d_in[6];
  const float* bq_in         = (const float*)d_in[7];
  const float* Wi_in         = (const float*)d_in[8];
  const float* bi_in         = (const float*)d_in[9];
  const float* A_log         = (const float*)d_in[10];
  const float* Bw            = (const float*)d_in[11];
  const float* Cw            = (const float*)d_in[12];
  const float* Dp            = (const float*)d_in[13];
  const float* ln_g          = (const float*)d_in[14];
  const float* ln_b          = (const float*)d_in[15];
  const float* gate_w        = (const float*)d_in[16];
  const float* gate_b        = (const float*)d_in[17];
  const float* in_proj_w     = (const float*)d_in[18];
  const float* in_proj_b     = (const float*)d_in[19];
  const float* out_w         = (const float*)d_in[20];
  const float* out_b         = (const float*)d_in[21];
  const float* dec_w1        = (const float*)d_in[22];
  const float* dec_b1        = (const float*)d_in[23];
  const float* dec_w2        = (const float*)d_in[24];
  const float* dec_b2        = (const float*)d_in[25];

  unsigned short* us = (unsigned short*)d_ws;
  float* seq = (float*)us;                 // 8,388,608 f = 16,777,216 us
  unsigned short* xnh = us + 16777216;     // 8,388,608
  unsigned short* xnl = xnh + 8388608;     // 8,388,608
  unsigned short* qhp = xnl + 8388608;     // 4,194,304
  unsigned short* qlp = qhp + 4194304;     // 4,194,304
  unsigned short* kvh = qlp + 4194304;     // 8,388,608
  unsigned short* kvl = kvh + 8388608;     // 8,388,608
  float* BuT = (float*)(kvl + 8388608);    // 262,144 f
  float* hsT = BuT + 262144;               // 262,144 f
  unsigned short* whi = (unsigned short*)(hsT + 262144);  // 589,824
  unsigned short* wlo = whi + 589824;      // 589,824
  unsigned short* Weh = wlo + 589824;      // 32,768
  unsigned short* Wel = Weh + 32768;       // 32,768
  float* obuf = (float*)xnh;               // alias: xn planes dead after layers
  float* attb = (float*)qhp;               // alias: q planes dead after attn
  float* hrel = (float*)kvh;               // alias: kv planes dead after attn

  wconv_k<<<288, 256, 0, stream>>>(gate_w, in_proj_w, out_w, dec_w1, whi, wlo);
  wconv2_k<<<128, 256, 0, stream>>>(Wi_in, Wq_in, Weh, Wel);
  embed_k<<<512, 256, 0, stream>>>(sparse_coords, sparse_values, query_coords,
                                   t_arr, noise, B_f, bq_in, bi_in, Weh, Wel, seq);
  for (int l = 0; l < 4; ++l) {
    ln_bu_k<<<8192, 256, 0, stream>>>(seq, ln_g + l * 256, ln_b + l * 256,
                                      Bw + l * 2048, xnh, xnl, BuT);
    scan_k<<<32, 256, 0, stream>>>(BuT, A_log + l * 8, hsT);
    mgemm_k<2, 1><<<dim3(2, 256), 256, 0, stream>>>(
        xnh, xnl, whi + l * 65536, wlo + l * 65536, gate_b + l * 256, seq, nullptr,
        256, 30, 0, 0, hsT, Cw + l * 2048, Dp + l * 256);
  }
  mgemm_k<3, 0><<<dim3(2, 128), 256, 0, stream>>>(
      seq, nullptr, whi + 262144, wlo + 262144, in_proj_b, qhp, qlp,
      256, 10, 2048, 1024, nullptr, nullptr, nullptr);
  mgemm_k<3, 0><<<dim3(4, 128), 256, 0, stream>>>(
      seq, nullptr, whi + 327680, wlo + 327680, in_proj_b + 256, kvh, kvl,
      512, 10, 2048, 0, nullptr, nullptr, nullptr);
  attn_k<<<512, 256, 0, stream>>>(qhp, qlp, kvh, kvl, obuf);
  mgemm_k<0, 0><<<dim3(2, 128), 256, 0, stream>>>(
      obuf, nullptr, whi + 458752, wlo + 458752, out_b, attb, nullptr,
      256, 30, 0, 0, nullptr, nullptr, nullptr);
  mgemm_k<1, 0><<<dim3(2, 128), 256, 0, stream>>>(
      attb, nullptr, whi + 524288, wlo + 524288, dec_b1, hrel, nullptr,
      256, 30, 0, 0, nullptr, nullptr, nullptr);
  dec2_k<<<4096, 256, 0, stream>>>(hrel, dec_w2, dec_b2, (float*)d_out);
}

// Round 9
// 702.940 us; speedup vs baseline: 1.0567x; 1.0567x over previous
//
#include <hip/hip_runtime.h>
#include <math.h>

// MAMBAFlow split-bf16 MFMA, round 9.
// = round 8 mgemm/pipeline + attn reverted to 64 q-rows/block (1024 blocks,
// 4/CU) with (a) bank-rotated Vt stores + uint2 P stores (round 8, proven
// conflicts 8.4M->1.0M) and (b) XCD-locality swizzle bid = qt*64 + bh so all
// q-tiles of one (b,h) share bid%8 -> same XCD L2 (kills 192 MB KV re-fetch).

typedef float floatx4 __attribute__((ext_vector_type(4)));
typedef short shortx8 __attribute__((ext_vector_type(8)));

__device__ __forceinline__ unsigned short f2bf(float f) {
  unsigned u = __builtin_bit_cast(unsigned, f);
  u += 0x7FFFu + ((u >> 16) & 1u);  // RNE
  return (unsigned short)(u >> 16);
}
__device__ __forceinline__ float bf2f(unsigned short h) {
  unsigned u = ((unsigned)h) << 16;
  return __builtin_bit_cast(float, u);
}
__device__ __forceinline__ void split8(float4 a, float4 b, uint4& uh, uint4& ul) {
  float fv[8] = {a.x, a.y, a.z, a.w, b.x, b.y, b.z, b.w};
  unsigned hh[8], ll[8];
#pragma unroll
  for (int j = 0; j < 8; ++j) {
    unsigned short h = f2bf(fv[j]);
    hh[j] = h;
    ll[j] = f2bf(fv[j] - bf2f(h));
  }
  uh = make_uint4(hh[0] | (hh[1] << 16), hh[2] | (hh[3] << 16),
                  hh[4] | (hh[5] << 16), hh[6] | (hh[7] << 16));
  ul = make_uint4(ll[0] | (ll[1] << 16), ll[2] | (ll[3] << 16),
                  ll[4] | (ll[5] << 16), ll[6] | (ll[7] << 16));
}
__device__ __forceinline__ shortx8 lds_frag(const unsigned short* S, int row, int u) {
  uint4 v = *(const uint4*)(S + row * 64 + ((u ^ (row & 7)) << 3));
  return __builtin_bit_cast(shortx8, v);
}
__device__ __forceinline__ shortx8 gfrag(const unsigned short* p) {
  return __builtin_bit_cast(shortx8, *(const uint4*)p);
}
__device__ __forceinline__ floatx4 mfma16(shortx8 a, shortx8 b, floatx4 c) {
  return __builtin_amdgcn_mfma_f32_16x16x32_bf16(a, b, c, 0, 0, 0);
}
__device__ __forceinline__ float wave_sum64(float v) {
#pragma unroll
  for (int m = 1; m < 64; m <<= 1) v += __shfl_xor(v, m);
  return v;
}

// ---------------- weights fp32 -> split bf16 planes ----------------
__global__ __launch_bounds__(256) void wconv_k(
    const float* __restrict__ gw, const float* __restrict__ ipw,
    const float* __restrict__ ow, const float* __restrict__ d1w,
    unsigned short* __restrict__ dh, unsigned short* __restrict__ dl) {
  int i = (blockIdx.x * 256 + threadIdx.x) * 8;
  const float* src;
  if (i < 262144) src = gw + i;
  else if (i < 458752) src = ipw + (i - 262144);
  else if (i < 524288) src = ow + (i - 458752);
  else src = d1w + (i - 524288);
  uint4 uh, ul;
  split8(*(const float4*)src, *(const float4*)(src + 4), uh, ul);
  *(uint4*)(dh + i) = uh;
  *(uint4*)(dl + i) = ul;
}

// ---------------- embed weights: [256][33] -> split planes [2][256][64] ----------------
__global__ __launch_bounds__(256) void wconv2_k(
    const float* __restrict__ Wi, const float* __restrict__ Wq,
    unsigned short* __restrict__ eh, unsigned short* __restrict__ el) {
  int idx = blockIdx.x * 256 + threadIdx.x;
  int sel = idx >> 14, rem = idx & 16383;
  int row = rem >> 6, k = rem & 63;
  float v = 0.f;
  if (k < 33) v = (sel ? Wq : Wi)[row * 33 + k];
  unsigned short h = f2bf(v);
  eh[idx] = h;
  el[idx] = f2bf(v - bf2f(h));
}

// ---------------- embed via MFMA: 64 tokens/block ----------------
__global__ __launch_bounds__(256) void embed_k(
    const float* __restrict__ sc, const float* __restrict__ sv,
    const float* __restrict__ qc, const float* __restrict__ tarr,
    const float* __restrict__ noise, const float* __restrict__ Bf,
    const float* __restrict__ bq, const float* __restrict__ bi,
    const unsigned short* __restrict__ Weh, const unsigned short* __restrict__ Wel,
    float* __restrict__ seq) {
  __shared__ unsigned short Ah[64 * 64];
  __shared__ unsigned short Al[64 * 64];
  __shared__ float teb[256];
  int tid = threadIdx.x;
  int bid = blockIdx.x;
  int chunk = bid & 15, half = (bid >> 4) & 1, b = bid >> 5;
  int rowbase = b * 2048 + half * 1024 + chunk * 64;
  {
    uint4 z = make_uint4(0, 0, 0, 0);
    *(uint4*)(Ah + tid * 8) = z;
    *(uint4*)(Ah + 2048 + tid * 8) = z;
    *(uint4*)(Al + tid * 8) = z;
    *(uint4*)(Al + 2048 + tid * 8) = z;
  }
  {
    float t = tarr[b];
    int dd = tid & 127;
    float e = t * __expf((float)dd * -0.07252236513367074f);
    float v = (tid < 128) ? sinf(e) : cosf(e);
    teb[tid] = v + (half ? bq : bi)[tid];
  }
  __syncthreads();
  {
    int tok = tid >> 2;
    int n = chunk * 64 + tok;
    const float* cp = (half ? qc : sc) + (size_t)(b * 1024 + n) * 2;
    float cx = cp[0], cy = cp[1];
#pragma unroll
    for (int jj = 0; jj < 4; ++jj) {
      int fr = (tid & 3) * 4 + jj;
      float px = cx * Bf[fr] + cy * Bf[16 + fr];
      float s = sinf(px), c = cosf(px);
      unsigned short sh = f2bf(s), ch = f2bf(c);
      int ks = fr, kc = 16 + fr;
      Ah[tok * 64 + (((ks >> 3) ^ (tok & 7)) << 3) + (ks & 7)] = sh;
      Al[tok * 64 + (((ks >> 3) ^ (tok & 7)) << 3) + (ks & 7)] = f2bf(s - bf2f(sh));
      Ah[tok * 64 + (((kc >> 3) ^ (tok & 7)) << 3) + (kc & 7)] = ch;
      Al[tok * 64 + (((kc >> 3) ^ (tok & 7)) << 3) + (kc & 7)] = f2bf(c - bf2f(ch));
    }
    if ((tid & 3) == 0) {
      float vv = (half ? noise : sv)[b * 1024 + n];
      unsigned short vh = f2bf(vv);
      Ah[tok * 64 + ((4 ^ (tok & 7)) << 3)] = vh;
      Al[tok * 64 + ((4 ^ (tok & 7)) << 3)] = f2bf(vv - bf2f(vh));
    }
  }
  __syncthreads();
  int w = tid >> 6, lane = tid & 63, lm = lane & 15, quad = lane >> 4;
  const unsigned short* Wb = Weh + half * 16384;
  const unsigned short* Wbl = Wel + half * 16384;
  floatx4 acc[4][4] = {};
#pragma unroll
  for (int s = 0; s < 2; ++s) {
    shortx8 afh[4], afl[4];
#pragma unroll
    for (int i = 0; i < 4; ++i) {
      afh[i] = lds_frag(Ah, i * 16 + lm, s * 4 + quad);
      afl[i] = lds_frag(Al, i * 16 + lm, s * 4 + quad);
    }
#pragma unroll
    for (int n = 0; n < 4; ++n) {
      int wr = w * 64 + n * 16 + lm;
      shortx8 bh = gfrag(Wb + wr * 64 + (s * 4 + quad) * 8);
      shortx8 bl = gfrag(Wbl + wr * 64 + (s * 4 + quad) * 8);
#pragma unroll
      for (int i = 0; i < 4; ++i) {
        acc[i][n] = mfma16(afl[i], bh, acc[i][n]);
        acc[i][n] = mfma16(afh[i], bl, acc[i][n]);
        acc[i][n] = mfma16(afh[i], bh, acc[i][n]);
      }
    }
  }
#pragma unroll
  for (int i = 0; i < 4; ++i)
#pragma unroll
    for (int n = 0; n < 4; ++n) {
      int col = w * 64 + n * 16 + lm;
      float te = teb[col];
#pragma unroll
      for (int r = 0; r < 4; ++r) {
        int tok = i * 16 + quad * 4 + r;
        seq[(size_t)(rowbase + tok) * 256 + col] = acc[i][n][r] + te;
      }
    }
}

// ---------------- layernorm + split xn planes + transposed Bu ----------------
__global__ __launch_bounds__(256) void ln_bu_k(
    const float* __restrict__ seq, const float* __restrict__ g,
    const float* __restrict__ be, const float* __restrict__ Bw,
    unsigned short* __restrict__ xnh, unsigned short* __restrict__ xnl,
    float* __restrict__ BuT) {
  int tid = threadIdx.x;
  int row = blockIdx.x * 4 + (tid >> 6);
  int lane = tid & 63;
  float4 x = *(const float4*)(seq + (size_t)row * 256 + lane * 4);
  float s1 = x.x + x.y + x.z + x.w;
  float s2 = x.x * x.x + x.y * x.y + x.z * x.z + x.w * x.w;
#pragma unroll
  for (int mk = 1; mk < 64; mk <<= 1) {
    s1 += __shfl_xor(s1, mk);
    s2 += __shfl_xor(s2, mk);
  }
  float mu = s1 * (1.0f / 256.0f);
  float var = s2 * (1.0f / 256.0f) - mu * mu;
  float rs = rsqrtf(var + 1e-5f);
  float4 gg = *(const float4*)(g + lane * 4);
  float4 bb = *(const float4*)(be + lane * 4);
  float xn0 = (x.x - mu) * rs * gg.x + bb.x;
  float xn1 = (x.y - mu) * rs * gg.y + bb.y;
  float xn2 = (x.z - mu) * rs * gg.z + bb.z;
  float xn3 = (x.w - mu) * rs * gg.w + bb.w;
  unsigned short h0 = f2bf(xn0), h1 = f2bf(xn1), h2 = f2bf(xn2), h3 = f2bf(xn3);
  *(ushort4*)(xnh + (size_t)row * 256 + lane * 4) = make_ushort4(h0, h1, h2, h3);
  *(ushort4*)(xnl + (size_t)row * 256 + lane * 4) =
      make_ushort4(f2bf(xn0 - bf2f(h0)), f2bf(xn1 - bf2f(h1)),
                   f2bf(xn2 - bf2f(h2)), f2bf(xn3 - bf2f(h3)));
#pragma unroll
  for (int s = 0; s < 8; ++s) {
    float4 bw = *(const float4*)(Bw + s * 256 + lane * 4);
    float p = xn0 * bw.x + xn1 * bw.y + xn2 * bw.z + xn3 * bw.w;
#pragma unroll
    for (int mk = 1; mk < 64; mk <<= 1) p += __shfl_xor(p, mk);
    if (lane == 0) BuT[(size_t)s * 32768 + row] = p;
  }
}

// ---------------- SSM scan: one wave per (b,s), coalesced ----------------
__global__ __launch_bounds__(256) void scan_k(
    const float* __restrict__ BuT, const float* __restrict__ A_log,
    float* __restrict__ hsT) {
  int tid = threadIdx.x;
  int wid = blockIdx.x * 4 + (tid >> 6);
  int lane = tid & 63;
  int b = wid >> 3, s = wid & 7;
  float A = -fminf(fmaxf(expf(A_log[s]), 1e-8f), 10.0f);
  float abar = expf(A * (1.0f / 2048.0f));
  size_t base = (size_t)s * 32768 + b * 2048 + lane * 32;
  const float4* bu4 = (const float4*)(BuT + base);
  float4 v[8];
#pragma unroll
  for (int k = 0; k < 8; ++k) v[k] = bu4[k];
  float bl = 0.f;
#pragma unroll
  for (int k = 0; k < 8; ++k) {
    bl = abar * bl + v[k].x;
    bl = abar * bl + v[k].y;
    bl = abar * bl + v[k].z;
    bl = abar * bl + v[k].w;
  }
  float a = expf(A * (32.0f / 2048.0f));
  float bb = bl;
#pragma unroll
  for (int off = 1; off < 64; off <<= 1) {
    float pa = __shfl_up(a, (unsigned)off);
    float pb = __shfl_up(bb, (unsigned)off);
    if (lane >= off) { bb = a * pb + bb; a = a * pa; }
  }
  float h = __shfl_up(bb, 1u);
  if (lane == 0) h = 0.f;
  float4* hp4 = (float4*)(hsT + base);
#pragma unroll
  for (int k = 0; k < 8; ++k) {
    float h0 = abar * h + v[k].x;
    float h1 = abar * h0 + v[k].y;
    float h2 = abar * h1 + v[k].z;
    float h3 = abar * h2 + v[k].w;
    hp4[k] = make_float4(h0, h1, h2, h3);
    h = h3;
  }
}

// ---------------- split-bf16 MFMA GEMM (LDS-staged 128x128) ----------------
// ASPLIT=1: A as hi/lo ushort planes. ASPLIT=0: A fp32, split in-register.
// MODE 0: fp32 C=acc+bias  MODE 1: relu  MODE 2: gate-SSM epilogue into seq
// MODE 3: split-plane ushort outputs (Ch,Cl)
template <int MODE, int ASPLIT>
__global__ __launch_bounds__(256, 2) void mgemm_k(
    const void* __restrict__ Aptr, const unsigned short* __restrict__ Alp,
    const unsigned short* __restrict__ Wh, const unsigned short* __restrict__ Wl,
    const float* __restrict__ bias, void* __restrict__ C0, void* __restrict__ C1,
    int ldc, int aClog, int aStride, int aBase,
    const float* __restrict__ hsT, const float* __restrict__ Cw,
    const float* __restrict__ Dp) {
  __shared__ unsigned short Ash[128 * 64];
  __shared__ unsigned short Asl[128 * 64];
  __shared__ unsigned short Bsh[128 * 64];
  __shared__ unsigned short Bsl[128 * 64];
  int tid = threadIdx.x;
  int n0 = blockIdx.x * 128, m0 = blockIdx.y * 128;
  int w = tid >> 6, lane = tid & 63;
  int wm = w & 1, wn = w >> 1;
  int lm = lane & 15, quad = lane >> 4;
  int sr = tid >> 3, scu = tid & 7;
  unsigned aMask = (1u << aClog) - 1u;
  floatx4 acc[4][4] = {};
  for (int kc = 0; kc < 4; ++kc) {
    uint4 ah[4], al[4], wh[4], wl[4];
#pragma unroll
    for (int p = 0; p < 4; ++p) {
      int am = m0 + sr + p * 32;
      int grow = ((am >> aClog) * aStride) + aBase + (int)((unsigned)am & aMask);
      if (ASPLIT) {
        const unsigned short* pa = (const unsigned short*)Aptr + (size_t)grow * 256 + kc * 64 + scu * 8;
        ah[p] = *(const uint4*)pa;
        al[p] = *(const uint4*)(Alp + (pa - (const unsigned short*)Aptr));
      } else {
        const float* pa = (const float*)Aptr + (size_t)grow * 256 + kc * 64 + scu * 8;
        split8(*(const float4*)pa, *(const float4*)(pa + 4), ah[p], al[p]);
      }
      const unsigned short* pw = Wh + (size_t)(n0 + sr + p * 32) * 256 + kc * 64 + scu * 8;
      wh[p] = *(const uint4*)pw;
      wl[p] = *(const uint4*)(Wl + (pw - Wh));
    }
    __syncthreads();
#pragma unroll
    for (int p = 0; p < 4; ++p) {
      int r = sr + p * 32;
      int off = r * 64 + ((scu ^ (r & 7)) << 3);
      *(uint4*)(Ash + off) = ah[p];
      *(uint4*)(Asl + off) = al[p];
      *(uint4*)(Bsh + off) = wh[p];
      *(uint4*)(Bsl + off) = wl[p];
    }
    __syncthreads();
#pragma unroll
    for (int s = 0; s < 2; ++s) {
      shortx8 afh[4], afl[4], bfh[4], bfl[4];
#pragma unroll
      for (int i = 0; i < 4; ++i) {
        int rr = wm * 64 + i * 16 + lm;
        afh[i] = lds_frag(Ash, rr, s * 4 + quad);
        afl[i] = lds_frag(Asl, rr, s * 4 + quad);
      }
#pragma unroll
      for (int n = 0; n < 4; ++n) {
        int rr = wn * 64 + n * 16 + lm;
        bfh[n] = lds_frag(Bsh, rr, s * 4 + quad);
        bfl[n] = lds_frag(Bsl, rr, s * 4 + quad);
      }
#pragma unroll
      for (int i = 0; i < 4; ++i)
#pragma unroll
        for (int n = 0; n < 4; ++n) {
          acc[i][n] = mfma16(afl[i], bfh[n], acc[i][n]);
          acc[i][n] = mfma16(afh[i], bfl[n], acc[i][n]);
          acc[i][n] = mfma16(afh[i], bfh[n], acc[i][n]);
        }
    }
  }
  if (MODE == 2) {
    float cw[4][8], dp4[4], bi4[4];
#pragma unroll
    for (int n = 0; n < 4; ++n) {
      int col = n0 + wn * 64 + n * 16 + lm;
      float4 c0 = *(const float4*)(Cw + (size_t)col * 8);
      float4 c1 = *(const float4*)(Cw + (size_t)col * 8 + 4);
      cw[n][0] = c0.x; cw[n][1] = c0.y; cw[n][2] = c0.z; cw[n][3] = c0.w;
      cw[n][4] = c1.x; cw[n][5] = c1.y; cw[n][6] = c1.z; cw[n][7] = c1.w;
      dp4[n] = Dp[col];
      bi4[n] = bias[col];
    }
    float* seqp = (float*)C0;
    const unsigned short* Ahp = (const unsigned short*)Aptr;
#pragma unroll
    for (int i = 0; i < 4; ++i)
#pragma unroll
      for (int r = 0; r < 4; ++r) {
        int row = m0 + wm * 64 + i * 16 + quad * 4 + r;
        float hv[8];
#pragma unroll
        for (int s = 0; s < 8; ++s) hv[s] = hsT[(size_t)s * 32768 + row];
        float* srow = seqp + (size_t)row * 256;
#pragma unroll
        for (int n = 0; n < 4; ++n) {
          int col = n0 + wn * 64 + n * 16 + lm;
          float xg = acc[i][n][r] + bi4[n];
          float gt = 1.0f / (1.0f + __expf(-xg));
          float xv = bf2f(Ahp[(size_t)row * 256 + col]) + bf2f(Alp[(size_t)row * 256 + col]);
          float y = dp4[n] * xv;
#pragma unroll
          for (int s = 0; s < 8; ++s) y += hv[s] * cw[n][s];
          srow[col] += gt * y;
        }
      }
  } else if (MODE == 3) {
    unsigned short* Ch = (unsigned short*)C0;
    unsigned short* Cl = (unsigned short*)C1;
#pragma unroll
    for (int i = 0; i < 4; ++i)
#pragma unroll
      for (int r = 0; r < 4; ++r) {
        int row = m0 + wm * 64 + i * 16 + quad * 4 + r;
#pragma unroll
        for (int n = 0; n < 4; ++n) {
          int col = n0 + wn * 64 + n * 16 + lm;
          float v = acc[i][n][r] + bias[col];
          unsigned short h = f2bf(v);
          Ch[(size_t)row * ldc + col] = h;
          Cl[(size_t)row * ldc + col] = f2bf(v - bf2f(h));
        }
      }
  } else {
    float* Cf = (float*)C0;
#pragma unroll
    for (int i = 0; i < 4; ++i)
#pragma unroll
      for (int r = 0; r < 4; ++r) {
        int row = m0 + wm * 64 + i * 16 + quad * 4 + r;
#pragma unroll
        for (int n = 0; n < 4; ++n) {
          int col = n0 + wn * 64 + n * 16 + lm;
          float v = acc[i][n][r] + bias[col];
          if (MODE == 1) v = fmaxf(v, 0.0f);
          Cf[(size_t)row * ldc + col] = v;
        }
      }
  }
}

// ---------------- flash attention: split-QK, hi-V, S^T, per-lane softmax ----------------
// Block = 64 q rows of one (b,h). bid = qt*64 + bh: all 16 q-tiles of one
// (b,h) share bid%8 -> same XCD -> KV stays in that XCD's L2 (3 MB/XCD).
__global__ __launch_bounds__(256, 4) void attn_k(
    const unsigned short* __restrict__ qh, const unsigned short* __restrict__ ql,
    const unsigned short* __restrict__ kvh, const unsigned short* __restrict__ kvl,
    float* __restrict__ ob) {
  __shared__ unsigned short Ksh[64 * 64];
  __shared__ unsigned short Ksl[64 * 64];
  __shared__ unsigned short Vt[64 * 64];      // V transposed [d][key], bf16-hi
  __shared__ unsigned short Ps[4 * 16 * 64];  // per-wave P [16 q][64 key]
  int tid = threadIdx.x;
  int bid = blockIdx.x;
  int bh = bid & 63, qt = bid >> 6;   // XCD-locality: bid%8 == bh%8
  int h = bh & 3, b = bh >> 2;
  int w = tid >> 6, lane = tid & 63, lm = lane & 15, quad = lane >> 4;
  int sr = tid >> 3, scu = tid & 7;
  unsigned short* Pw = Ps + w * 1024;
  shortx8 qfh[2], qfl[2];
  {
    size_t qoff = (size_t)(b * 1024 + qt * 64 + w * 16 + lm) * 256 + h * 64;
#pragma unroll
    for (int s = 0; s < 2; ++s) {
      qfh[s] = gfrag(qh + qoff + s * 32 + quad * 8);
      qfl[s] = gfrag(ql + qoff + s * 32 + quad * 8);
    }
  }
  float lac = 0.f;
  floatx4 oacc[4] = {};
  const size_t kvbase = ((size_t)(b * 1024)) * 512 + h * 64;
  const float sc_l2 = 0.125f * 1.44269504089f;  // 1/sqrt(64)*log2(e)
  int vg = tid & 7, vk = (tid >> 3) * 2;
  for (int kt = 0; kt < 16; ++kt) {
    uint4 kh4[2], kl4[2];
#pragma unroll
    for (int p = 0; p < 2; ++p) {
      int r = sr + p * 32;
      size_t a = kvbase + (size_t)(kt * 64 + r) * 512 + scu * 8;
      kh4[p] = *(const uint4*)(kvh + a);
      kl4[p] = *(const uint4*)(kvl + a);
    }
    uint4 vv0 = *(const uint4*)(kvh + kvbase + (size_t)(kt * 64 + vk) * 512 + 256 + vg * 8);
    uint4 vv1 = *(const uint4*)(kvh + kvbase + (size_t)(kt * 64 + vk + 1) * 512 + 256 + vg * 8);
    __syncthreads();  // prior iter's K/V fragment reads complete
#pragma unroll
    for (int p = 0; p < 2; ++p) {
      int r = sr + p * 32;
      int off = r * 64 + ((scu ^ (r & 7)) << 3);
      *(uint4*)(Ksh + off) = kh4[p];
      *(uint4*)(Ksl + off) = kl4[p];
    }
    {
      shortx8 s0 = __builtin_bit_cast(shortx8, vv0);
      shortx8 s1 = __builtin_bit_cast(shortx8, vv1);
#pragma unroll
      for (int jj = 0; jj < 8; ++jj) {
        int j = (jj + vg) & 7;     // bank-rotated store: no 8-way conflict
        int d = vg * 8 + j;
        unsigned pack = ((unsigned)(unsigned short)s0[j]) |
                        (((unsigned)(unsigned short)s1[j]) << 16);
        *(unsigned*)(Vt + d * 64 + (((vk >> 3) ^ (d & 7)) << 3) + (vk & 7)) = pack;
      }
    }
    __syncthreads();
    // S^T = K · Q^T : rows = keys, cols = q
    floatx4 sacc[4] = {};
#pragma unroll
    for (int s = 0; s < 2; ++s) {
#pragma unroll
      for (int m = 0; m < 4; ++m) {
        shortx8 kfh = lds_frag(Ksh, m * 16 + lm, s * 4 + quad);
        shortx8 kfl = lds_frag(Ksl, m * 16 + lm, s * 4 + quad);
        sacc[m] = mfma16(kfl, qfh[s], sacc[m]);
        sacc[m] = mfma16(kfh, qfl[s], sacc[m]);
        sacc[m] = mfma16(kfh, qfh[s], sacc[m]);
      }
    }
#pragma unroll
    for (int m = 0; m < 4; ++m) {
      float p0 = exp2f(sacc[m][0] * sc_l2 - 12.0f);
      float p1 = exp2f(sacc[m][1] * sc_l2 - 12.0f);
      float p2 = exp2f(sacc[m][2] * sc_l2 - 12.0f);
      float p3 = exp2f(sacc[m][3] * sc_l2 - 12.0f);
      lac += (p0 + p1) + (p2 + p3);
      int u = (m * 2 + (quad >> 1)) ^ (lm & 7);
      unsigned short* base = Pw + lm * 64 + u * 8 + (quad & 1) * 4;
      *(uint2*)base = make_uint2(((unsigned)f2bf(p0)) | (((unsigned)f2bf(p1)) << 16),
                                 ((unsigned)f2bf(p2)) | (((unsigned)f2bf(p3)) << 16));
    }
#pragma unroll
    for (int s = 0; s < 2; ++s) {
      shortx8 pf = lds_frag(Pw, lm, s * 4 + quad);
#pragma unroll
      for (int n = 0; n < 4; ++n) {
        shortx8 vf = lds_frag(Vt, n * 16 + lm, s * 4 + quad);
        oacc[n] = mfma16(pf, vf, oacc[n]);
      }
    }
  }
  lac += __shfl_xor(lac, 16);
  lac += __shfl_xor(lac, 32);
  const size_t obase = ((size_t)(b * 1024 + qt * 64 + w * 16)) * 256 + h * 64;
#pragma unroll
  for (int r = 0; r < 4; ++r) {
    int row = quad * 4 + r;
    float inv = 1.0f / __shfl(lac, row);
#pragma unroll
    for (int n = 0; n < 4; ++n)
      ob[obase + (size_t)row * 256 + n * 16 + lm] = oacc[n][r] * inv;
  }
}

// ---------------- final projection ----------------
__global__ __launch_bounds__(256) void dec2_k(const float* __restrict__ hb,
                                              const float* __restrict__ w2,
                                              const float* __restrict__ b2,
                                              float* __restrict__ out) {
  int tid = threadIdx.x;
  int m = blockIdx.x * 4 + (tid >> 6);
  int lane = tid & 63;
  float4 h4 = *(const float4*)(hb + (size_t)m * 256 + lane * 4);
  float4 w4 = *(const float4*)(w2 + lane * 4);
  float v = h4.x * w4.x + h4.y * w4.y + h4.z * w4.z + h4.w * w4.w;
  v = wave_sum64(v);
  if (lane == 0) out[m] = v + b2[0];
}

extern "C" void kernel_launch(void* const* d_in, const int* in_sizes, int n_in,
                              void* d_out, int out_size, void* d_ws, size_t ws_size,
                              hipStream_t stream) {
  const float* sparse_coords = (const float*)d_in[0];
  const float* sparse_values = (const float*)d_in[1];
  const float* query_coords  = (const float*)d_in[2];
  const float* t_arr         = (const float*)d_in[3];
  const float* noise         = (const float*)d_in[4];
  const float* B_f           = (const float*)d_in[5];
  const float* Wq_in         = (const float*)d_in[6];
  const float* bq_in         = (const float*)d_in[7];
  const float* Wi_in         = (const float*)d_in[8];
  const float* bi_in         = (const float*)d_in[9];
  const float* A_log         = (const float*)d_in[10];
  const float* Bw            = (const float*)d_in[11];
  const float* Cw            = (const float*)d_in[12];
  const float* Dp            = (const float*)d_in[13];
  const float* ln_g          = (const float*)d_in[14];
  const float* ln_b          = (const float*)d_in[15];
  const float* gate_w        = (const float*)d_in[16];
  const float* gate_b        = (const float*)d_in[17];
  const float* in_proj_w     = (const float*)d_in[18];
  const float* in_proj_b     = (const float*)d_in[19];
  const float* out_w         = (const float*)d_in[20];
  const float* out_b         = (const float*)d_in[21];
  const float* dec_w1        = (const float*)d_in[22];
  const float* dec_b1        = (const float*)d_in[23];
  const float* dec_w2        = (const float*)d_in[24];
  const float* dec_b2        = (const float*)d_in[25];

  unsigned short* us = (unsigned short*)d_ws;
  float* seq = (float*)us;                 // 8,388,608 f = 16,777,216 us
  unsigned short* xnh = us + 16777216;     // 8,388,608
  unsigned short* xnl = xnh + 8388608;     // 8,388,608
  unsigned short* qhp = xnl + 8388608;     // 4,194,304
  unsigned short* qlp = qhp + 4194304;     // 4,194,304
  unsigned short* kvh = qlp + 4194304;     // 8,388,608
  unsigned short* kvl = kvh + 8388608;     // 8,388,608
  float* BuT = (float*)(kvl + 8388608);    // 262,144 f
  float* hsT = BuT + 262144;               // 262,144 f
  unsigned short* whi = (unsigned short*)(hsT + 262144);  // 589,824
  unsigned short* wlo = whi + 589824;      // 589,824
  unsigned short* Weh = wlo + 589824;      // 32,768
  unsigned short* Wel = Weh + 32768;       // 32,768
  float* obuf = (float*)xnh;               // alias: xn planes dead after layers
  float* attb = (float*)qhp;               // alias: q planes dead after attn
  float* hrel = (float*)kvh;               // alias: kv planes dead after attn

  wconv_k<<<288, 256, 0, stream>>>(gate_w, in_proj_w, out_w, dec_w1, whi, wlo);
  wconv2_k<<<128, 256, 0, stream>>>(Wi_in, Wq_in, Weh, Wel);
  embed_k<<<512, 256, 0, stream>>>(sparse_coords, sparse_values, query_coords,
                                   t_arr, noise, B_f, bq_in, bi_in, Weh, Wel, seq);
  for (int l = 0; l < 4; ++l) {
    ln_bu_k<<<8192, 256, 0, stream>>>(seq, ln_g + l * 256, ln_b + l * 256,
                                      Bw + l * 2048, xnh, xnl, BuT);
    scan_k<<<32, 256, 0, stream>>>(BuT, A_log + l * 8, hsT);
    mgemm_k<2, 1><<<dim3(2, 256), 256, 0, stream>>>(
        xnh, xnl, whi + l * 65536, wlo + l * 65536, gate_b + l * 256, seq, nullptr,
        256, 30, 0, 0, hsT, Cw + l * 2048, Dp + l * 256);
  }
  mgemm_k<3, 0><<<dim3(2, 128), 256, 0, stream>>>(
      seq, nullptr, whi + 262144, wlo + 262144, in_proj_b, qhp, qlp,
      256, 10, 2048, 1024, nullptr, nullptr, nullptr);
  mgemm_k<3, 0><<<dim3(4, 128), 256, 0, stream>>>(
      seq, nullptr, whi + 327680, wlo + 327680, in_proj_b + 256, kvh, kvl,
      512, 10, 2048, 0, nullptr, nullptr, nullptr);
  attn_k<<<1024, 256, 0, stream>>>(qhp, qlp, kvh, kvl, obuf);
  mgemm_k<0, 0><<<dim3(2, 128), 256, 0, stream>>>(
      obuf, nullptr, whi + 458752, wlo + 458752, out_b, attb, nullptr,
      256, 30, 0, 0, nullptr, nullptr, nullptr);
  mgemm_k<1, 0><<<dim3(2, 128), 256, 0, stream>>>(
      attb, nullptr, whi + 524288, wlo + 524288, dec_b1, hrel, nullptr,
      256, 30, 0, 0, nullptr, nullptr, nullptr);
  dec2_k<<<4096, 256, 0, stream>>>(hrel, dec_w2, dec_b2, (float*)d_out);
}

// Round 10
// 701.463 us; speedup vs baseline: 1.0589x; 1.0021x over previous
//
#include <hip/hip_runtime.h>
#include <math.h>

// MAMBAFlow split-bf16 MFMA, round 10.
// = round 9 + software prefetch in mgemm_k and attn_k K-loops:
//   {sync; LDS-store; sync; load k+1 into regs; compute k}
// so global-load latency overlaps MFMA/softmax compute instead of heading
// the critical path. No numerics changes (absmax stays 2.44e-4 floor).

typedef float floatx4 __attribute__((ext_vector_type(4)));
typedef short shortx8 __attribute__((ext_vector_type(8)));

__device__ __forceinline__ unsigned short f2bf(float f) {
  unsigned u = __builtin_bit_cast(unsigned, f);
  u += 0x7FFFu + ((u >> 16) & 1u);  // RNE
  return (unsigned short)(u >> 16);
}
__device__ __forceinline__ float bf2f(unsigned short h) {
  unsigned u = ((unsigned)h) << 16;
  return __builtin_bit_cast(float, u);
}
__device__ __forceinline__ void split8(float4 a, float4 b, uint4& uh, uint4& ul) {
  float fv[8] = {a.x, a.y, a.z, a.w, b.x, b.y, b.z, b.w};
  unsigned hh[8], ll[8];
#pragma unroll
  for (int j = 0; j < 8; ++j) {
    unsigned short h = f2bf(fv[j]);
    hh[j] = h;
    ll[j] = f2bf(fv[j] - bf2f(h));
  }
  uh = make_uint4(hh[0] | (hh[1] << 16), hh[2] | (hh[3] << 16),
                  hh[4] | (hh[5] << 16), hh[6] | (hh[7] << 16));
  ul = make_uint4(ll[0] | (ll[1] << 16), ll[2] | (ll[3] << 16),
                  ll[4] | (ll[5] << 16), ll[6] | (ll[7] << 16));
}
__device__ __forceinline__ shortx8 lds_frag(const unsigned short* S, int row, int u) {
  uint4 v = *(const uint4*)(S + row * 64 + ((u ^ (row & 7)) << 3));
  return __builtin_bit_cast(shortx8, v);
}
__device__ __forceinline__ shortx8 gfrag(const unsigned short* p) {
  return __builtin_bit_cast(shortx8, *(const uint4*)p);
}
__device__ __forceinline__ floatx4 mfma16(shortx8 a, shortx8 b, floatx4 c) {
  return __builtin_amdgcn_mfma_f32_16x16x32_bf16(a, b, c, 0, 0, 0);
}
__device__ __forceinline__ float wave_sum64(float v) {
#pragma unroll
  for (int m = 1; m < 64; m <<= 1) v += __shfl_xor(v, m);
  return v;
}

// ---------------- weights fp32 -> split bf16 planes ----------------
__global__ __launch_bounds__(256) void wconv_k(
    const float* __restrict__ gw, const float* __restrict__ ipw,
    const float* __restrict__ ow, const float* __restrict__ d1w,
    unsigned short* __restrict__ dh, unsigned short* __restrict__ dl) {
  int i = (blockIdx.x * 256 + threadIdx.x) * 8;
  const float* src;
  if (i < 262144) src = gw + i;
  else if (i < 458752) src = ipw + (i - 262144);
  else if (i < 524288) src = ow + (i - 458752);
  else src = d1w + (i - 524288);
  uint4 uh, ul;
  split8(*(const float4*)src, *(const float4*)(src + 4), uh, ul);
  *(uint4*)(dh + i) = uh;
  *(uint4*)(dl + i) = ul;
}

// ---------------- embed weights: [256][33] -> split planes [2][256][64] ----------------
__global__ __launch_bounds__(256) void wconv2_k(
    const float* __restrict__ Wi, const float* __restrict__ Wq,
    unsigned short* __restrict__ eh, unsigned short* __restrict__ el) {
  int idx = blockIdx.x * 256 + threadIdx.x;
  int sel = idx >> 14, rem = idx & 16383;
  int row = rem >> 6, k = rem & 63;
  float v = 0.f;
  if (k < 33) v = (sel ? Wq : Wi)[row * 33 + k];
  unsigned short h = f2bf(v);
  eh[idx] = h;
  el[idx] = f2bf(v - bf2f(h));
}

// ---------------- embed via MFMA: 64 tokens/block ----------------
__global__ __launch_bounds__(256) void embed_k(
    const float* __restrict__ sc, const float* __restrict__ sv,
    const float* __restrict__ qc, const float* __restrict__ tarr,
    const float* __restrict__ noise, const float* __restrict__ Bf,
    const float* __restrict__ bq, const float* __restrict__ bi,
    const unsigned short* __restrict__ Weh, const unsigned short* __restrict__ Wel,
    float* __restrict__ seq) {
  __shared__ unsigned short Ah[64 * 64];
  __shared__ unsigned short Al[64 * 64];
  __shared__ float teb[256];
  int tid = threadIdx.x;
  int bid = blockIdx.x;
  int chunk = bid & 15, half = (bid >> 4) & 1, b = bid >> 5;
  int rowbase = b * 2048 + half * 1024 + chunk * 64;
  {
    uint4 z = make_uint4(0, 0, 0, 0);
    *(uint4*)(Ah + tid * 8) = z;
    *(uint4*)(Ah + 2048 + tid * 8) = z;
    *(uint4*)(Al + tid * 8) = z;
    *(uint4*)(Al + 2048 + tid * 8) = z;
  }
  {
    float t = tarr[b];
    int dd = tid & 127;
    float e = t * __expf((float)dd * -0.07252236513367074f);
    float v = (tid < 128) ? sinf(e) : cosf(e);
    teb[tid] = v + (half ? bq : bi)[tid];
  }
  __syncthreads();
  {
    int tok = tid >> 2;
    int n = chunk * 64 + tok;
    const float* cp = (half ? qc : sc) + (size_t)(b * 1024 + n) * 2;
    float cx = cp[0], cy = cp[1];
#pragma unroll
    for (int jj = 0; jj < 4; ++jj) {
      int fr = (tid & 3) * 4 + jj;
      float px = cx * Bf[fr] + cy * Bf[16 + fr];
      float s = sinf(px), c = cosf(px);
      unsigned short sh = f2bf(s), ch = f2bf(c);
      int ks = fr, kc = 16 + fr;
      Ah[tok * 64 + (((ks >> 3) ^ (tok & 7)) << 3) + (ks & 7)] = sh;
      Al[tok * 64 + (((ks >> 3) ^ (tok & 7)) << 3) + (ks & 7)] = f2bf(s - bf2f(sh));
      Ah[tok * 64 + (((kc >> 3) ^ (tok & 7)) << 3) + (kc & 7)] = ch;
      Al[tok * 64 + (((kc >> 3) ^ (tok & 7)) << 3) + (kc & 7)] = f2bf(c - bf2f(ch));
    }
    if ((tid & 3) == 0) {
      float vv = (half ? noise : sv)[b * 1024 + n];
      unsigned short vh = f2bf(vv);
      Ah[tok * 64 + ((4 ^ (tok & 7)) << 3)] = vh;
      Al[tok * 64 + ((4 ^ (tok & 7)) << 3)] = f2bf(vv - bf2f(vh));
    }
  }
  __syncthreads();
  int w = tid >> 6, lane = tid & 63, lm = lane & 15, quad = lane >> 4;
  const unsigned short* Wb = Weh + half * 16384;
  const unsigned short* Wbl = Wel + half * 16384;
  floatx4 acc[4][4] = {};
#pragma unroll
  for (int s = 0; s < 2; ++s) {
    shortx8 afh[4], afl[4];
#pragma unroll
    for (int i = 0; i < 4; ++i) {
      afh[i] = lds_frag(Ah, i * 16 + lm, s * 4 + quad);
      afl[i] = lds_frag(Al, i * 16 + lm, s * 4 + quad);
    }
#pragma unroll
    for (int n = 0; n < 4; ++n) {
      int wr = w * 64 + n * 16 + lm;
      shortx8 bh = gfrag(Wb + wr * 64 + (s * 4 + quad) * 8);
      shortx8 bl = gfrag(Wbl + wr * 64 + (s * 4 + quad) * 8);
#pragma unroll
      for (int i = 0; i < 4; ++i) {
        acc[i][n] = mfma16(afl[i], bh, acc[i][n]);
        acc[i][n] = mfma16(afh[i], bl, acc[i][n]);
        acc[i][n] = mfma16(afh[i], bh, acc[i][n]);
      }
    }
  }
#pragma unroll
  for (int i = 0; i < 4; ++i)
#pragma unroll
    for (int n = 0; n < 4; ++n) {
      int col = w * 64 + n * 16 + lm;
      float te = teb[col];
#pragma unroll
      for (int r = 0; r < 4; ++r) {
        int tok = i * 16 + quad * 4 + r;
        seq[(size_t)(rowbase + tok) * 256 + col] = acc[i][n][r] + te;
      }
    }
}

// ---------------- layernorm + split xn planes + transposed Bu ----------------
__global__ __launch_bounds__(256) void ln_bu_k(
    const float* __restrict__ seq, const float* __restrict__ g,
    const float* __restrict__ be, const float* __restrict__ Bw,
    unsigned short* __restrict__ xnh, unsigned short* __restrict__ xnl,
    float* __restrict__ BuT) {
  int tid = threadIdx.x;
  int row = blockIdx.x * 4 + (tid >> 6);
  int lane = tid & 63;
  float4 x = *(const float4*)(seq + (size_t)row * 256 + lane * 4);
  float s1 = x.x + x.y + x.z + x.w;
  float s2 = x.x * x.x + x.y * x.y + x.z * x.z + x.w * x.w;
#pragma unroll
  for (int mk = 1; mk < 64; mk <<= 1) {
    s1 += __shfl_xor(s1, mk);
    s2 += __shfl_xor(s2, mk);
  }
  float mu = s1 * (1.0f / 256.0f);
  float var = s2 * (1.0f / 256.0f) - mu * mu;
  float rs = rsqrtf(var + 1e-5f);
  float4 gg = *(const float4*)(g + lane * 4);
  float4 bb = *(const float4*)(be + lane * 4);
  float xn0 = (x.x - mu) * rs * gg.x + bb.x;
  float xn1 = (x.y - mu) * rs * gg.y + bb.y;
  float xn2 = (x.z - mu) * rs * gg.z + bb.z;
  float xn3 = (x.w - mu) * rs * gg.w + bb.w;
  unsigned short h0 = f2bf(xn0), h1 = f2bf(xn1), h2 = f2bf(xn2), h3 = f2bf(xn3);
  *(ushort4*)(xnh + (size_t)row * 256 + lane * 4) = make_ushort4(h0, h1, h2, h3);
  *(ushort4*)(xnl + (size_t)row * 256 + lane * 4) =
      make_ushort4(f2bf(xn0 - bf2f(h0)), f2bf(xn1 - bf2f(h1)),
                   f2bf(xn2 - bf2f(h2)), f2bf(xn3 - bf2f(h3)));
#pragma unroll
  for (int s = 0; s < 8; ++s) {
    float4 bw = *(const float4*)(Bw + s * 256 + lane * 4);
    float p = xn0 * bw.x + xn1 * bw.y + xn2 * bw.z + xn3 * bw.w;
#pragma unroll
    for (int mk = 1; mk < 64; mk <<= 1) p += __shfl_xor(p, mk);
    if (lane == 0) BuT[(size_t)s * 32768 + row] = p;
  }
}

// ---------------- SSM scan: one wave per (b,s), coalesced ----------------
__global__ __launch_bounds__(256) void scan_k(
    const float* __restrict__ BuT, const float* __restrict__ A_log,
    float* __restrict__ hsT) {
  int tid = threadIdx.x;
  int wid = blockIdx.x * 4 + (tid >> 6);
  int lane = tid & 63;
  int b = wid >> 3, s = wid & 7;
  float A = -fminf(fmaxf(expf(A_log[s]), 1e-8f), 10.0f);
  float abar = expf(A * (1.0f / 2048.0f));
  size_t base = (size_t)s * 32768 + b * 2048 + lane * 32;
  const float4* bu4 = (const float4*)(BuT + base);
  float4 v[8];
#pragma unroll
  for (int k = 0; k < 8; ++k) v[k] = bu4[k];
  float bl = 0.f;
#pragma unroll
  for (int k = 0; k < 8; ++k) {
    bl = abar * bl + v[k].x;
    bl = abar * bl + v[k].y;
    bl = abar * bl + v[k].z;
    bl = abar * bl + v[k].w;
  }
  float a = expf(A * (32.0f / 2048.0f));
  float bb = bl;
#pragma unroll
  for (int off = 1; off < 64; off <<= 1) {
    float pa = __shfl_up(a, (unsigned)off);
    float pb = __shfl_up(bb, (unsigned)off);
    if (lane >= off) { bb = a * pb + bb; a = a * pa; }
  }
  float h = __shfl_up(bb, 1u);
  if (lane == 0) h = 0.f;
  float4* hp4 = (float4*)(hsT + base);
#pragma unroll
  for (int k = 0; k < 8; ++k) {
    float h0 = abar * h + v[k].x;
    float h1 = abar * h0 + v[k].y;
    float h2 = abar * h1 + v[k].z;
    float h3 = abar * h2 + v[k].w;
    hp4[k] = make_float4(h0, h1, h2, h3);
    h = h3;
  }
}

// ---------------- split-bf16 MFMA GEMM (LDS-staged 128x128, prefetched) ----------------
// K-loop: {sync; LDS-store; sync; prefetch kc+1; compute kc}.
// ASPLIT=1: A as hi/lo ushort planes. ASPLIT=0: A fp32, split in-register.
// MODE 0: fp32 C=acc+bias  MODE 1: relu  MODE 2: gate-SSM epilogue into seq
// MODE 3: split-plane ushort outputs (Ch,Cl)
template <int MODE, int ASPLIT>
__global__ __launch_bounds__(256, 2) void mgemm_k(
    const void* __restrict__ Aptr, const unsigned short* __restrict__ Alp,
    const unsigned short* __restrict__ Wh, const unsigned short* __restrict__ Wl,
    const float* __restrict__ bias, void* __restrict__ C0, void* __restrict__ C1,
    int ldc, int aClog, int aStride, int aBase,
    const float* __restrict__ hsT, const float* __restrict__ Cw,
    const float* __restrict__ Dp) {
  __shared__ unsigned short Ash[128 * 64];
  __shared__ unsigned short Asl[128 * 64];
  __shared__ unsigned short Bsh[128 * 64];
  __shared__ unsigned short Bsl[128 * 64];
  int tid = threadIdx.x;
  int n0 = blockIdx.x * 128, m0 = blockIdx.y * 128;
  int w = tid >> 6, lane = tid & 63;
  int wm = w & 1, wn = w >> 1;
  int lm = lane & 15, quad = lane >> 4;
  int sr = tid >> 3, scu = tid & 7;
  unsigned aMask = (1u << aClog) - 1u;
  int garow[4];
#pragma unroll
  for (int p = 0; p < 4; ++p) {
    int am = m0 + sr + p * 32;
    garow[p] = ((am >> aClog) * aStride) + aBase + (int)((unsigned)am & aMask);
  }
  uint4 ah[4], al[4], wh[4], wl[4];
  auto load_chunk = [&](int kc) {
#pragma unroll
    for (int p = 0; p < 4; ++p) {
      if (ASPLIT) {
        const unsigned short* pa =
            (const unsigned short*)Aptr + (size_t)garow[p] * 256 + kc * 64 + scu * 8;
        ah[p] = *(const uint4*)pa;
        al[p] = *(const uint4*)(Alp + (pa - (const unsigned short*)Aptr));
      } else {
        const float* pa = (const float*)Aptr + (size_t)garow[p] * 256 + kc * 64 + scu * 8;
        split8(*(const float4*)pa, *(const float4*)(pa + 4), ah[p], al[p]);
      }
      const unsigned short* pw = Wh + (size_t)(n0 + sr + p * 32) * 256 + kc * 64 + scu * 8;
      wh[p] = *(const uint4*)pw;
      wl[p] = *(const uint4*)(Wl + (pw - Wh));
    }
  };
  load_chunk(0);
  floatx4 acc[4][4] = {};
  for (int kc = 0; kc < 4; ++kc) {
    __syncthreads();  // prior compute's LDS reads complete
#pragma unroll
    for (int p = 0; p < 4; ++p) {
      int r = sr + p * 32;
      int off = r * 64 + ((scu ^ (r & 7)) << 3);
      *(uint4*)(Ash + off) = ah[p];
      *(uint4*)(Asl + off) = al[p];
      *(uint4*)(Bsh + off) = wh[p];
      *(uint4*)(Bsl + off) = wl[p];
    }
    __syncthreads();  // staged tile visible
    if (kc < 3) load_chunk(kc + 1);  // prefetch overlaps compute below
#pragma unroll
    for (int s = 0; s < 2; ++s) {
      shortx8 afh[4], afl[4], bfh[4], bfl[4];
#pragma unroll
      for (int i = 0; i < 4; ++i) {
        int rr = wm * 64 + i * 16 + lm;
        afh[i] = lds_frag(Ash, rr, s * 4 + quad);
        afl[i] = lds_frag(Asl, rr, s * 4 + quad);
      }
#pragma unroll
      for (int n = 0; n < 4; ++n) {
        int rr = wn * 64 + n * 16 + lm;
        bfh[n] = lds_frag(Bsh, rr, s * 4 + quad);
        bfl[n] = lds_frag(Bsl, rr, s * 4 + quad);
      }
#pragma unroll
      for (int i = 0; i < 4; ++i)
#pragma unroll
        for (int n = 0; n < 4; ++n) {
          acc[i][n] = mfma16(afl[i], bfh[n], acc[i][n]);
          acc[i][n] = mfma16(afh[i], bfl[n], acc[i][n]);
          acc[i][n] = mfma16(afh[i], bfh[n], acc[i][n]);
        }
    }
  }
  if (MODE == 2) {
    float cw[4][8], dp4[4], bi4[4];
#pragma unroll
    for (int n = 0; n < 4; ++n) {
      int col = n0 + wn * 64 + n * 16 + lm;
      float4 c0 = *(const float4*)(Cw + (size_t)col * 8);
      float4 c1 = *(const float4*)(Cw + (size_t)col * 8 + 4);
      cw[n][0] = c0.x; cw[n][1] = c0.y; cw[n][2] = c0.z; cw[n][3] = c0.w;
      cw[n][4] = c1.x; cw[n][5] = c1.y; cw[n][6] = c1.z; cw[n][7] = c1.w;
      dp4[n] = Dp[col];
      bi4[n] = bias[col];
    }
    float* seqp = (float*)C0;
    const unsigned short* Ahp = (const unsigned short*)Aptr;
#pragma unroll
    for (int i = 0; i < 4; ++i)
#pragma unroll
      for (int r = 0; r < 4; ++r) {
        int row = m0 + wm * 64 + i * 16 + quad * 4 + r;
        float hv[8];
#pragma unroll
        for (int s = 0; s < 8; ++s) hv[s] = hsT[(size_t)s * 32768 + row];
        float* srow = seqp + (size_t)row * 256;
#pragma unroll
        for (int n = 0; n < 4; ++n) {
          int col = n0 + wn * 64 + n * 16 + lm;
          float xg = acc[i][n][r] + bi4[n];
          float gt = 1.0f / (1.0f + __expf(-xg));
          float xv = bf2f(Ahp[(size_t)row * 256 + col]) + bf2f(Alp[(size_t)row * 256 + col]);
          float y = dp4[n] * xv;
#pragma unroll
          for (int s = 0; s < 8; ++s) y += hv[s] * cw[n][s];
          srow[col] += gt * y;
        }
      }
  } else if (MODE == 3) {
    unsigned short* Ch = (unsigned short*)C0;
    unsigned short* Cl = (unsigned short*)C1;
#pragma unroll
    for (int i = 0; i < 4; ++i)
#pragma unroll
      for (int r = 0; r < 4; ++r) {
        int row = m0 + wm * 64 + i * 16 + quad * 4 + r;
#pragma unroll
        for (int n = 0; n < 4; ++n) {
          int col = n0 + wn * 64 + n * 16 + lm;
          float v = acc[i][n][r] + bias[col];
          unsigned short h = f2bf(v);
          Ch[(size_t)row * ldc + col] = h;
          Cl[(size_t)row * ldc + col] = f2bf(v - bf2f(h));
        }
      }
  } else {
    float* Cf = (float*)C0;
#pragma unroll
    for (int i = 0; i < 4; ++i)
#pragma unroll
      for (int r = 0; r < 4; ++r) {
        int row = m0 + wm * 64 + i * 16 + quad * 4 + r;
#pragma unroll
        for (int n = 0; n < 4; ++n) {
          int col = n0 + wn * 64 + n * 16 + lm;
          float v = acc[i][n][r] + bias[col];
          if (MODE == 1) v = fmaxf(v, 0.0f);
          Cf[(size_t)row * ldc + col] = v;
        }
      }
  }
}

// ---------------- flash attention: split-QK, hi-V, S^T, per-lane softmax ----------------
// Block = 64 q rows of one (b,h). bid = qt*64 + bh keeps all q-tiles of one
// (b,h) on one XCD. K-loop prefetches kt+1's K/V global loads over compute.
__global__ __launch_bounds__(256, 4) void attn_k(
    const unsigned short* __restrict__ qh, const unsigned short* __restrict__ ql,
    const unsigned short* __restrict__ kvh, const unsigned short* __restrict__ kvl,
    float* __restrict__ ob) {
  __shared__ unsigned short Ksh[64 * 64];
  __shared__ unsigned short Ksl[64 * 64];
  __shared__ unsigned short Vt[64 * 64];      // V transposed [d][key], bf16-hi
  __shared__ unsigned short Ps[4 * 16 * 64];  // per-wave P [16 q][64 key]
  int tid = threadIdx.x;
  int bid = blockIdx.x;
  int bh = bid & 63, qt = bid >> 6;   // XCD-locality: bid%8 == bh%8
  int h = bh & 3, b = bh >> 2;
  int w = tid >> 6, lane = tid & 63, lm = lane & 15, quad = lane >> 4;
  int sr = tid >> 3, scu = tid & 7;
  unsigned short* Pw = Ps + w * 1024;
  shortx8 qfh[2], qfl[2];
  {
    size_t qoff = (size_t)(b * 1024 + qt * 64 + w * 16 + lm) * 256 + h * 64;
#pragma unroll
    for (int s = 0; s < 2; ++s) {
      qfh[s] = gfrag(qh + qoff + s * 32 + quad * 8);
      qfl[s] = gfrag(ql + qoff + s * 32 + quad * 8);
    }
  }
  float lac = 0.f;
  floatx4 oacc[4] = {};
  const size_t kvbase = ((size_t)(b * 1024)) * 512 + h * 64;
  const float sc_l2 = 0.125f * 1.44269504089f;  // 1/sqrt(64)*log2(e)
  int vg = tid & 7, vk = (tid >> 3) * 2;
  uint4 kh4[2], kl4[2], vv0, vv1;
  auto load_kv = [&](int kt) {
#pragma unroll
    for (int p = 0; p < 2; ++p) {
      int r = sr + p * 32;
      size_t a = kvbase + (size_t)(kt * 64 + r) * 512 + scu * 8;
      kh4[p] = *(const uint4*)(kvh + a);
      kl4[p] = *(const uint4*)(kvl + a);
    }
    vv0 = *(const uint4*)(kvh + kvbase + (size_t)(kt * 64 + vk) * 512 + 256 + vg * 8);
    vv1 = *(const uint4*)(kvh + kvbase + (size_t)(kt * 64 + vk + 1) * 512 + 256 + vg * 8);
  };
  load_kv(0);
  for (int kt = 0; kt < 16; ++kt) {
    __syncthreads();  // prior iter's Ksh/Vt fragment reads complete
#pragma unroll
    for (int p = 0; p < 2; ++p) {
      int r = sr + p * 32;
      int off = r * 64 + ((scu ^ (r & 7)) << 3);
      *(uint4*)(Ksh + off) = kh4[p];
      *(uint4*)(Ksl + off) = kl4[p];
    }
    {
      shortx8 s0 = __builtin_bit_cast(shortx8, vv0);
      shortx8 s1 = __builtin_bit_cast(shortx8, vv1);
#pragma unroll
      for (int jj = 0; jj < 8; ++jj) {
        int j = (jj + vg) & 7;     // bank-rotated store: no 8-way conflict
        int d = vg * 8 + j;
        unsigned pack = ((unsigned)(unsigned short)s0[j]) |
                        (((unsigned)(unsigned short)s1[j]) << 16);
        *(unsigned*)(Vt + d * 64 + (((vk >> 3) ^ (d & 7)) << 3) + (vk & 7)) = pack;
      }
    }
    __syncthreads();  // staged K/V visible
    if (kt < 15) load_kv(kt + 1);  // prefetch overlaps compute below
    // S^T = K · Q^T : rows = keys, cols = q
    floatx4 sacc[4] = {};
#pragma unroll
    for (int s = 0; s < 2; ++s) {
#pragma unroll
      for (int m = 0; m < 4; ++m) {
        shortx8 kfh = lds_frag(Ksh, m * 16 + lm, s * 4 + quad);
        shortx8 kfl = lds_frag(Ksl, m * 16 + lm, s * 4 + quad);
        sacc[m] = mfma16(kfl, qfh[s], sacc[m]);
        sacc[m] = mfma16(kfh, qfl[s], sacc[m]);
        sacc[m] = mfma16(kfh, qfh[s], sacc[m]);
      }
    }
#pragma unroll
    for (int m = 0; m < 4; ++m) {
      float p0 = exp2f(sacc[m][0] * sc_l2 - 12.0f);
      float p1 = exp2f(sacc[m][1] * sc_l2 - 12.0f);
      float p2 = exp2f(sacc[m][2] * sc_l2 - 12.0f);
      float p3 = exp2f(sacc[m][3] * sc_l2 - 12.0f);
      lac += (p0 + p1) + (p2 + p3);
      int u = (m * 2 + (quad >> 1)) ^ (lm & 7);
      unsigned short* base = Pw + lm * 64 + u * 8 + (quad & 1) * 4;
      *(uint2*)base = make_uint2(((unsigned)f2bf(p0)) | (((unsigned)f2bf(p1)) << 16),
                                 ((unsigned)f2bf(p2)) | (((unsigned)f2bf(p3)) << 16));
    }
#pragma unroll
    for (int s = 0; s < 2; ++s) {
      shortx8 pf = lds_frag(Pw, lm, s * 4 + quad);
#pragma unroll
      for (int n = 0; n < 4; ++n) {
        shortx8 vf = lds_frag(Vt, n * 16 + lm, s * 4 + quad);
        oacc[n] = mfma16(pf, vf, oacc[n]);
      }
    }
  }
  lac += __shfl_xor(lac, 16);
  lac += __shfl_xor(lac, 32);
  const size_t obase = ((size_t)(b * 1024 + qt * 64 + w * 16)) * 256 + h * 64;
#pragma unroll
  for (int r = 0; r < 4; ++r) {
    int row = quad * 4 + r;
    float inv = 1.0f / __shfl(lac, row);
#pragma unroll
    for (int n = 0; n < 4; ++n)
      ob[obase + (size_t)row * 256 + n * 16 + lm] = oacc[n][r] * inv;
  }
}

// ---------------- final projection ----------------
__global__ __launch_bounds__(256) void dec2_k(const float* __restrict__ hb,
                                              const float* __restrict__ w2,
                                              const float* __restrict__ b2,
                                              float* __restrict__ out) {
  int tid = threadIdx.x;
  int m = blockIdx.x * 4 + (tid >> 6);
  int lane = tid & 63;
  float4 h4 = *(const float4*)(hb + (size_t)m * 256 + lane * 4);
  float4 w4 = *(const float4*)(w2 + lane * 4);
  float v = h4.x * w4.x + h4.y * w4.y + h4.z * w4.z + h4.w * w4.w;
  v = wave_sum64(v);
  if (lane == 0) out[m] = v + b2[0];
}

extern "C" void kernel_launch(void* const* d_in, const int* in_sizes, int n_in,
                              void* d_out, int out_size, void* d_ws, size_t ws_size,
                              hipStream_t stream) {
  const float* sparse_coords = (const float*)d_in[0];
  const float* sparse_values = (const float*)d_in[1];
  const float* query_coords  = (const float*)d_in[2];
  const float* t_arr         = (const float*)d_in[3];
  const float* noise         = (const float*)d_in[4];
  const float* B_f           = (const float*)d_in[5];
  const float* Wq_in         = (const float*)d_in[6];
  const float* bq_in         = (const float*)d_in[7];
  const float* Wi_in         = (const float*)d_in[8];
  const float* bi_in         = (const float*)d_in[9];
  const float* A_log         = (const float*)d_in[10];
  const float* Bw            = (const float*)d_in[11];
  const float* Cw            = (const float*)d_in[12];
  const float* Dp            = (const float*)d_in[13];
  const float* ln_g          = (const float*)d_in[14];
  const float* ln_b          = (const float*)d_in[15];
  const float* gate_w        = (const float*)d_in[16];
  const float* gate_b        = (const float*)d_in[17];
  const float* in_proj_w     = (const float*)d_in[18];
  const float* in_proj_b     = (const float*)d_in[19];
  const float* out_w         = (const float*)d_in[20];
  const float* out_b         = (const float*)d_in[21];
  const float* dec_w1        = (const float*)d_in[22];
  const float* dec_b1        = (const float*)d_in[23];
  const float* dec_w2        = (const float*)d_in[24];
  const float* dec_b2        = (const float*)d_in[25];

  unsigned short* us = (unsigned short*)d_ws;
  float* seq = (float*)us;                 // 8,388,608 f = 16,777,216 us
  unsigned short* xnh = us + 16777216;     // 8,388,608
  unsigned short* xnl = xnh + 8388608;     // 8,388,608
  unsigned short* qhp = xnl + 8388608;     // 4,194,304
  unsigned short* qlp = qhp + 4194304;     // 4,194,304
  unsigned short* kvh = qlp + 4194304;     // 8,388,608
  unsigned short* kvl = kvh + 8388608;     // 8,388,608
  float* BuT = (float*)(kvl + 8388608);    // 262,144 f
  float* hsT = BuT + 262144;               // 262,144 f
  unsigned short* whi = (unsigned short*)(hsT + 262144);  // 589,824
  unsigned short* wlo = whi + 589824;      // 589,824
  unsigned short* Weh = wlo + 589824;      // 32,768
  unsigned short* Wel = Weh + 32768;       // 32,768
  float* obuf = (float*)xnh;               // alias: xn planes dead after layers
  float* attb = (float*)qhp;               // alias: q planes dead after attn
  float* hrel = (float*)kvh;               // alias: kv planes dead after attn

  wconv_k<<<288, 256, 0, stream>>>(gate_w, in_proj_w, out_w, dec_w1, whi, wlo);
  wconv2_k<<<128, 256, 0, stream>>>(Wi_in, Wq_in, Weh, Wel);
  embed_k<<<512, 256, 0, stream>>>(sparse_coords, sparse_values, query_coords,
                                   t_arr, noise, B_f, bq_in, bi_in, Weh, Wel, seq);
  for (int l = 0; l < 4; ++l) {
    ln_bu_k<<<8192, 256, 0, stream>>>(seq, ln_g + l * 256, ln_b + l * 256,
                                      Bw + l * 2048, xnh, xnl, BuT);
    scan_k<<<32, 256, 0, stream>>>(BuT, A_log + l * 8, hsT);
    mgemm_k<2, 1><<<dim3(2, 256), 256, 0, stream>>>(
        xnh, xnl, whi + l * 65536, wlo + l * 65536, gate_b + l * 256, seq, nullptr,
        256, 30, 0, 0, hsT, Cw + l * 2048, Dp + l * 256);
  }
  mgemm_k<3, 0><<<dim3(2, 128), 256, 0, stream>>>(
      seq, nullptr, whi + 262144, wlo + 262144, in_proj_b, qhp, qlp,
      256, 10, 2048, 1024, nullptr, nullptr, nullptr);
  mgemm_k<3, 0><<<dim3(4, 128), 256, 0, stream>>>(
      seq, nullptr, whi + 327680, wlo + 327680, in_proj_b + 256, kvh, kvl,
      512, 10, 2048, 0, nullptr, nullptr, nullptr);
  attn_k<<<1024, 256, 0, stream>>>(qhp, qlp, kvh, kvl, obuf);
  mgemm_k<0, 0><<<dim3(2, 128), 256, 0, stream>>>(
      obuf, nullptr, whi + 458752, wlo + 458752, out_b, attb, nullptr,
      256, 30, 0, 0, nullptr, nullptr, nullptr);
  mgemm_k<1, 0><<<dim3(2, 128), 256, 0, stream>>>(
      attb, nullptr, whi + 524288, wlo + 524288, dec_b1, hrel, nullptr,
      256, 30, 0, 0, nullptr, nullptr, nullptr);
  dec2_k<<<4096, 256, 0, stream>>>(hrel, dec_w2, dec_b2, (float*)d_out);
}